// Round 8
// baseline (111.653 us; speedup 1.0000x reference)
//
#include <hip/hip_runtime.h>
#include <math.h>

// SemiConv2d tropical conv: out = max_{ic,kh,kw} min(x_pad, K). f16-packed.
// R8: ic-pair-interleaved uint4 layout. ws entry xq2[(n*16+p)*98 + rowpad][j]
// = uint4 { win(ic=2p): (x[2j-1],x[2j]),(x[2j+1],x[2j+2]), win(ic=2p+1): same }.
// One dwordx4 feeds 2 ics; 4-ic macro step = one cluster of 6 dwordx4 ->
// 8 latency exposures/wave (R7: 16 @ ~920cyc exposed each). launch_bounds
// (192,4) lets the allocator hold the 24-VGPR batch. Keep: inline-asm
// v_pk_min/max (no IEEE canon), K SGPR-resident via "s" constraint,
// hp-fastest block order (XCD L2 locality), -inf baked edges.
// NOTE: harness poison-fill of 256MB d_ws (~43us) dominates dur_us overhead;
// main kernel time must be read by subtraction.

#define HH 96
#define WW 96
#define CIN 32
#define OCN 32
#define XQ_ROWS 98
#define XQ_W 48
#define XQ_SLICE (XQ_ROWS * XQ_W)              // uint4 units per ic-pair slice
#define XQ_TOTAL (8 * 16 * XQ_SLICE)           // uint4 elements total
#define K2_TOTAL (8 * 32 * 4 * 9)              // uint32 elements
#define WS_NEED ((size_t)XQ_TOTAL * 16 + (size_t)K2_TOTAL * 4)
#define NEGH2 0xFC00FC00u

typedef _Float16 h2 __attribute__((ext_vector_type(2)));

__device__ __forceinline__ uint32_t pkmin_vs(uint32_t x, uint32_t k) {
    uint32_t d;
    asm("v_pk_min_f16 %0, %1, %2" : "=v"(d) : "v"(x), "s"(k));
    return d;
}
__device__ __forceinline__ uint32_t pkmax(uint32_t a, uint32_t b) {
    uint32_t d;
    asm("v_pk_max_f16 %0, %1, %2" : "=v"(d) : "v"(a), "v"(b));
    return d;
}

__device__ __forceinline__ uint32_t packh2(float lo, float hi) {
    h2 p = {(_Float16)lo, (_Float16)hi};
    return __builtin_bit_cast(uint32_t, p);
}

__global__ __launch_bounds__(256) void setup_xq2(const float* __restrict__ x,
                                                 uint4* __restrict__ xq2) {
    int idx = blockIdx.x * 256 + threadIdx.x;   // over 8*16*98*48 = 602,112
    int j  = idx % XQ_W;
    int t  = idx / XQ_W;                        // (n*16+p)*98 + rowpad
    int hp = t % XQ_ROWS;
    int sp = t / XQ_ROWS;                       // n*16 + p
    int p  = sp % 16;
    int n  = sp / 16;
    int h  = hp - 1;
    bool hv = (h >= 0) && (h < HH);
    uint4 v;
    {
        const float* row = x + ((size_t)(n * CIN + 2 * p) * HH + (hv ? h : 0)) * WW;
        float a = (hv && j > 0)        ? row[2 * j - 1] : -INFINITY;
        float b = hv                   ? row[2 * j]     : -INFINITY;
        float c = hv                   ? row[2 * j + 1] : -INFINITY;
        float d = (hv && j < XQ_W - 1) ? row[2 * j + 2] : -INFINITY;
        v.x = packh2(a, b);
        v.y = packh2(c, d);
    }
    {
        const float* row = x + ((size_t)(n * CIN + 2 * p + 1) * HH + (hv ? h : 0)) * WW;
        float a = (hv && j > 0)        ? row[2 * j - 1] : -INFINITY;
        float b = hv                   ? row[2 * j]     : -INFINITY;
        float c = hv                   ? row[2 * j + 1] : -INFINITY;
        float d = (hv && j < XQ_W - 1) ? row[2 * j + 2] : -INFINITY;
        v.z = packh2(a, b);
        v.w = packh2(c, d);
    }
    xq2[idx] = v;
}

__global__ __launch_bounds__(256) void setup_k(const float* __restrict__ kk,
                                               uint32_t* __restrict__ k2) {
    int idx = blockIdx.x * 256 + threadIdx.x;   // over 9216
    int tap  = idx % 9;
    int ocin = (idx / 9) % 4;
    int ic   = (idx / 36) % CIN;
    int ocb  = idx / (36 * CIN);
    float v = kk[(((ocb * 4 + ocin) * CIN) + ic) * 9 + tap];
    _Float16 hv = (_Float16)v;
    h2 pk = {hv, hv};
    k2[idx] = __builtin_bit_cast(uint32_t, pk);
}

__global__ __launch_bounds__(192, 4) void semiconv_f16(const uint4* __restrict__ xq2,
                                                       const uint32_t* __restrict__ k2,
                                                       float* __restrict__ out) {
    const int tid = threadIdx.x;
    const int jj = tid % 48;          // w-pair 0..47
    const int hr = tid / 48;          // 0..3
    const int b  = blockIdx.x;
    const int hp  = b % 24;           // hp FASTEST -> XCD L2 locality (R4 win)
    const int t   = b / 24;
    const int ocb = t & 7;
    const int n   = t >> 3;
    const int h   = hp * 4 + hr;      // one output row per thread

    // padded row r = x row (h-1+r); output h uses padded rows h, h+1, h+2
    const uint4* xp = xq2 + ((size_t)(n * 16) * XQ_ROWS + h) * XQ_W + jj;
    const uint32_t* kp = k2 + (size_t)ocb * CIN * 36;

    uint32_t acc[4] = {NEGH2, NEGH2, NEGH2, NEGH2};

    for (int pp = 0; pp < 16; pp += 2) {      // 4 ics per macro step
        uint4 q[2][3];
#pragma unroll
        for (int u = 0; u < 2; ++u) {
            const uint4* base = xp + (size_t)(pp + u) * XQ_SLICE;
#pragma unroll
            for (int r = 0; r < 3; ++r)
                q[u][r] = base[r * XQ_W];
        }
#pragma unroll
        for (int u = 0; u < 2; ++u) {
#pragma unroll
            for (int e = 0; e < 2; ++e) {     // e=0: ic even (.x/.y), e=1: odd (.z/.w)
                uint32_t tap[9];
#pragma unroll
                for (int r = 0; r < 3; ++r) {
                    uint32_t lo = e ? q[u][r].z : q[u][r].x;
                    uint32_t hi = e ? q[u][r].w : q[u][r].y;
                    tap[r * 3 + 0] = lo;
                    tap[r * 3 + 1] = __builtin_amdgcn_alignbit(hi, lo, 16);
                    tap[r * 3 + 2] = hi;
                }
                const int ic = 2 * (pp + u) + e;
                const uint32_t* kq0 = kp + ic * 36;
#pragma unroll
                for (int oc = 0; oc < 4; ++oc) {
                    const uint32_t* kq = kq0 + oc * 9;   // uniform -> SGPRs
                    uint32_t m0 = pkmin_vs(tap[0], kq[0]);
                    uint32_t m1 = pkmin_vs(tap[1], kq[1]);
                    uint32_t m2 = pkmin_vs(tap[2], kq[2]);
                    uint32_t m3 = pkmin_vs(tap[3], kq[3]);
                    uint32_t m4 = pkmin_vs(tap[4], kq[4]);
                    uint32_t m5 = pkmin_vs(tap[5], kq[5]);
                    uint32_t m6 = pkmin_vs(tap[6], kq[6]);
                    uint32_t m7 = pkmin_vs(tap[7], kq[7]);
                    uint32_t m8 = pkmin_vs(tap[8], kq[8]);
                    uint32_t t01 = pkmax(m0, m1), t23 = pkmax(m2, m3);
                    uint32_t t45 = pkmax(m4, m5), t67 = pkmax(m6, m7);
                    uint32_t tt  = pkmax(pkmax(t01, t23), pkmax(t45, t67));
                    acc[oc] = pkmax(acc[oc], pkmax(tt, m8));
                }
            }
        }
    }

#pragma unroll
    for (int oc = 0; oc < 4; ++oc) {
        h2 a = __builtin_bit_cast(h2, acc[oc]);
        float2 v = make_float2((float)a.x, (float)a.y);
        *(float2*)(out + (((size_t)(n * OCN + ocb * 4 + oc)) * HH + h) * WW + 2 * jj) = v;
    }
}

// ---------- f32 fallback if ws is too small ----------
#define NEGINF (-INFINITY)
__global__ __launch_bounds__(192, 8) void semiconv2d_f32(
    const float* __restrict__ x, const float* __restrict__ kk, float* __restrict__ out)
{
    const int tid = threadIdx.x;
    const int w  = tid % WW;
    const int hr = tid / WW;
    const int b   = blockIdx.x;
    const int ocb = b & 7;
    const int hp  = (b >> 3) % 48;
    const int n   = (b >> 3) / 48;
    const int h   = hp * 2 + hr;
    const int oc0 = ocb * 4;
    float a0[4], a1[4], a2[4];
#pragma unroll
    for (int i = 0; i < 4; ++i) { a0[i] = NEGINF; a1[i] = NEGINF; a2[i] = NEGINF; }
    const bool vm = (h > 0), vp = (h < HH - 1);
    const int hm  = vm ? h - 1 : h;
    const int hpl = vp ? h + 1 : h;
    const int cm  = (w > 0) ? -1 : 0;
    const int cp  = (w < WW - 1) ? 1 : 0;
    const float* rm = x + ((size_t)(n * CIN) * HH + hm)  * WW + w;
    const float* r1 = x + ((size_t)(n * CIN) * HH + h)   * WW + w;
    const float* rp = x + ((size_t)(n * CIN) * HH + hpl) * WW + w;
#pragma unroll 2
    for (int ic = 0; ic < CIN; ++ic) {
        float r00 = vm ? rm[cm] : NEGINF, r01 = vm ? rm[0] : NEGINF, r02 = vm ? rm[cp] : NEGINF;
        float r10 = r1[cm], r11 = r1[0], r12 = r1[cp];
        float r20 = vp ? rp[cm] : NEGINF, r21 = vp ? rp[0] : NEGINF, r22 = vp ? rp[cp] : NEGINF;
#pragma unroll
        for (int oc = 0; oc < 4; ++oc) {
            const float* kq = kk + (size_t)(((oc0 + oc) * CIN + ic)) * 9;
            a0[oc] = fmaxf(fmaxf(a0[oc], fminf(r00, kq[0])), fmaxf(fminf(r10, kq[3]), fminf(r20, kq[6])));
            a1[oc] = fmaxf(fmaxf(a1[oc], fminf(r01, kq[1])), fmaxf(fminf(r11, kq[4]), fminf(r21, kq[7])));
            a2[oc] = fmaxf(fmaxf(a2[oc], fminf(r02, kq[2])), fmaxf(fminf(r12, kq[5]), fminf(r22, kq[8])));
        }
        rm += HH * WW; r1 += HH * WW; rp += HH * WW;
    }
#pragma unroll
    for (int oc = 0; oc < 4; ++oc) {
        float v0 = (w > 0)      ? a0[oc] : NEGINF;
        float v2 = (w < WW - 1) ? a2[oc] : NEGINF;
        out[(((size_t)(n * OCN + oc0 + oc)) * HH + h) * WW + w] = fmaxf(fmaxf(v0, a1[oc]), v2);
    }
}

extern "C" void kernel_launch(void* const* d_in, const int* in_sizes, int n_in,
                              void* d_out, int out_size, void* d_ws, size_t ws_size,
                              hipStream_t stream) {
    const float* x  = (const float*)d_in[0];
    const float* kk = (const float*)d_in[1];
    float* out      = (float*)d_out;
    if (ws_size >= WS_NEED) {
        uint4* xq2   = (uint4*)d_ws;
        uint32_t* k2 = (uint32_t*)(xq2 + XQ_TOTAL);
        setup_xq2<<<dim3(XQ_TOTAL / 256), dim3(256), 0, stream>>>(x, xq2);
        setup_k<<<dim3(K2_TOTAL / 256), dim3(256), 0, stream>>>(kk, k2);
        semiconv_f16<<<dim3(8 * 8 * 24), dim3(192), 0, stream>>>(xq2, k2, out);
    } else {
        semiconv2d_f32<<<dim3(8 * 48 * 8), dim3(192), 0, stream>>>(x, kk, out);
    }
}

// Round 9
// 104.629 us; speedup vs baseline: 1.0671x; 1.0671x over previous
//
#include <hip/hip_runtime.h>
#include <math.h>

// SemiConv2d tropical conv: out = max_{ic,kh,kw} min(x_pad, K). f16-packed.
// R9: kill the per-ic SCALAR K stall. R8 evidence: vector-load batching
// changes (R6->R8) were all neutral -- the stall is 32 per-ic s_load drains
// (SMEM is out-of-order => full lgkmcnt(0) before each 36-dword K use,
// ~300cyc x 32 un-pipelinable). Fix: stage block's K slice (4KB) in LDS once,
// pair-packed 2 taps/dword, read per (ic,oc) as ds_read_b128+b32 (uniform
// address => broadcast, no conflicts), consumed via VOP3P op_sel half-selects.
// Thread tile 4oc x 2h x 2w (16 outputs) amortizes K reads: LDS ~20K cyc/CU
// ~= VALU ~22K cyc/CU. Keep: inline-asm pk min/max (no IEEE canon), uint4
// ic-pair x layout (R8), hp-fastest block order (XCD L2 locality), -inf baked
// edges. NOTE: 256MB ws poison fill (~43us) is a fixed timed overhead.

#define HH 96
#define WW 96
#define CIN 32
#define OCN 32
#define XQ_ROWS 98
#define XQ_W 48
#define XQ_SLICE (XQ_ROWS * XQ_W)              // uint4 units per ic-pair slice
#define XQ_TOTAL (8 * 16 * XQ_SLICE)           // uint4 elements total
#define KP_TOTAL (8 * 32 * 4 * 8)              // uint32 elements (pair-packed)
#define WS_NEED ((size_t)XQ_TOTAL * 16 + (size_t)KP_TOTAL * 4)
#define NEGH2 0xFC00FC00u

typedef _Float16 h2 __attribute__((ext_vector_type(2)));

// result.lo = min(x.lo, k.lo); result.hi = min(x.hi, k.lo)
__device__ __forceinline__ uint32_t pkmin_lo(uint32_t x, uint32_t k) {
    uint32_t d;
    asm("v_pk_min_f16 %0, %1, %2 op_sel:[0,0] op_sel_hi:[1,0]" : "=v"(d) : "v"(x), "v"(k));
    return d;
}
// result.lo = min(x.lo, k.hi); result.hi = min(x.hi, k.hi)
__device__ __forceinline__ uint32_t pkmin_hi(uint32_t x, uint32_t k) {
    uint32_t d;
    asm("v_pk_min_f16 %0, %1, %2 op_sel:[0,1] op_sel_hi:[1,1]" : "=v"(d) : "v"(x), "v"(k));
    return d;
}
__device__ __forceinline__ uint32_t pkmin_vv(uint32_t a, uint32_t b) {
    uint32_t d;
    asm("v_pk_min_f16 %0, %1, %2" : "=v"(d) : "v"(a), "v"(b));
    return d;
}
__device__ __forceinline__ uint32_t pkmax(uint32_t a, uint32_t b) {
    uint32_t d;
    asm("v_pk_max_f16 %0, %1, %2" : "=v"(d) : "v"(a), "v"(b));
    return d;
}

__device__ __forceinline__ uint32_t packh2(float lo, float hi) {
    h2 p = {(_Float16)lo, (_Float16)hi};
    return __builtin_bit_cast(uint32_t, p);
}

__global__ __launch_bounds__(256) void setup_xq2(const float* __restrict__ x,
                                                 uint4* __restrict__ xq2) {
    int idx = blockIdx.x * 256 + threadIdx.x;   // over 8*16*98*48 = 602,112
    int j  = idx % XQ_W;
    int t  = idx / XQ_W;                        // (n*16+p)*98 + rowpad
    int hp = t % XQ_ROWS;
    int sp = t / XQ_ROWS;                       // n*16 + p
    int p  = sp % 16;
    int n  = sp / 16;
    int h  = hp - 1;
    bool hv = (h >= 0) && (h < HH);
    uint4 v;
    {
        const float* row = x + ((size_t)(n * CIN + 2 * p) * HH + (hv ? h : 0)) * WW;
        float a = (hv && j > 0)        ? row[2 * j - 1] : -INFINITY;
        float b = hv                   ? row[2 * j]     : -INFINITY;
        float c = hv                   ? row[2 * j + 1] : -INFINITY;
        float d = (hv && j < XQ_W - 1) ? row[2 * j + 2] : -INFINITY;
        v.x = packh2(a, b);
        v.y = packh2(c, d);
    }
    {
        const float* row = x + ((size_t)(n * CIN + 2 * p + 1) * HH + (hv ? h : 0)) * WW;
        float a = (hv && j > 0)        ? row[2 * j - 1] : -INFINITY;
        float b = hv                   ? row[2 * j]     : -INFINITY;
        float c = hv                   ? row[2 * j + 1] : -INFINITY;
        float d = (hv && j < XQ_W - 1) ? row[2 * j + 2] : -INFINITY;
        v.z = packh2(a, b);
        v.w = packh2(c, d);
    }
    xq2[idx] = v;
}

// pair-packed K: kp[ocb][ic][oc][8]: d0=(k0,k1) d1=(k2,k3) d2=(k4,k5)
// d3=(k6,k7) d4=(k8,k8) d5..7=0
__global__ __launch_bounds__(256) void setup_kp(const float* __restrict__ kk,
                                                uint32_t* __restrict__ kpck) {
    int idx = blockIdx.x * 256 + threadIdx.x;   // over 8192
    int d    = idx % 8;
    int oc   = (idx / 8) % 4;
    int ic   = (idx / 32) % CIN;
    int ocb  = idx / (32 * CIN);
    const float* kb = kk + (size_t)(((ocb * 4 + oc) * CIN) + ic) * 9;
    uint32_t v = 0;
    if (d < 4)      v = packh2(kb[2 * d], kb[2 * d + 1]);
    else if (d == 4) v = packh2(kb[8], kb[8]);
    kpck[idx] = v;
}

__global__ __launch_bounds__(192) void semiconv_f16(const uint4* __restrict__ xq2,
                                                    const uint32_t* __restrict__ kpck,
                                                    float* __restrict__ out) {
    __shared__ uint4 ks4[256];                  // 4KB: [ic][oc] -> 2 uint4
    const uint32_t* ks32 = (const uint32_t*)ks4;

    const int tid = threadIdx.x;
    const int jj = tid % 48;          // w-pair 0..47
    const int hr = tid / 48;          // 0..3
    const int b  = blockIdx.x;
    const int hp  = b % 12;           // hp FASTEST -> XCD L2 locality
    const int t   = b / 12;
    const int ocb = t & 7;
    const int n   = t >> 3;
    const int h0  = hp * 8 + hr * 2;  // output rows h0, h0+1

    // stage K slice: 256 uint4 by 192 threads
    const uint4* ksrc = (const uint4*)(kpck + (size_t)ocb * 1024);
    for (int i = tid; i < 256; i += 192) ks4[i] = ksrc[i];
    __syncthreads();

    // padded row r = x row (h0-1+r); outputs h0,h0+1 use padded rows 0..3
    const uint4* xp = xq2 + ((size_t)(n * 16) * XQ_ROWS + h0) * XQ_W + jj;

    uint32_t acc[4][2];
#pragma unroll
    for (int oc = 0; oc < 4; ++oc) { acc[oc][0] = NEGH2; acc[oc][1] = NEGH2; }

    for (int pp = 0; pp < 16; pp += 2) {        // 4 ics per macro step
        uint4 q[2][4];
#pragma unroll
        for (int u = 0; u < 2; ++u)
#pragma unroll
            for (int r = 0; r < 4; ++r)
                q[u][r] = xp[(size_t)(pp + u) * XQ_SLICE + r * XQ_W];

#pragma unroll
        for (int u = 0; u < 2; ++u) {
#pragma unroll
            for (int e = 0; e < 2; ++e) {       // e=0: ic even (.x/.y), e=1: odd
                const int ic = 2 * (pp + u) + e;
                uint32_t xt[4][3];
#pragma unroll
                for (int r = 0; r < 4; ++r) {
                    uint32_t lo = e ? q[u][r].z : q[u][r].x;
                    uint32_t hi = e ? q[u][r].w : q[u][r].y;
                    xt[r][0] = lo;
                    xt[r][1] = __builtin_amdgcn_alignbit(hi, lo, 16);
                    xt[r][2] = hi;
                }
#pragma unroll
                for (int oc = 0; oc < 4; ++oc) {
                    const int kidx = (ic * 4 + oc);
                    uint4 kd = ks4[kidx * 2];                // taps 0..7 (pairs)
                    uint32_t kc = ks32[kidx * 8 + 4];        // tap 8 (dup)
#pragma unroll
                    for (int o = 0; o < 2; ++o) {
                        uint32_t m0 = pkmin_lo(xt[o][0],     kd.x);
                        uint32_t m1 = pkmin_hi(xt[o][1],     kd.x);
                        uint32_t m2 = pkmin_lo(xt[o][2],     kd.y);
                        uint32_t m3 = pkmin_hi(xt[o + 1][0], kd.y);
                        uint32_t m4 = pkmin_lo(xt[o + 1][1], kd.z);
                        uint32_t m5 = pkmin_hi(xt[o + 1][2], kd.z);
                        uint32_t m6 = pkmin_lo(xt[o + 2][0], kd.w);
                        uint32_t m7 = pkmin_hi(xt[o + 2][1], kd.w);
                        uint32_t m8 = pkmin_vv(xt[o + 2][2], kc);
                        uint32_t t01 = pkmax(m0, m1), t23 = pkmax(m2, m3);
                        uint32_t t45 = pkmax(m4, m5), t67 = pkmax(m6, m7);
                        uint32_t tt  = pkmax(pkmax(t01, t23), pkmax(t45, t67));
                        acc[oc][o] = pkmax(acc[oc][o], pkmax(tt, m8));
                    }
                }
            }
        }
    }

#pragma unroll
    for (int oc = 0; oc < 4; ++oc)
#pragma unroll
        for (int o = 0; o < 2; ++o) {
            h2 a = __builtin_bit_cast(h2, acc[oc][o]);
            float2 v = make_float2((float)a.x, (float)a.y);
            *(float2*)(out + (((size_t)(n * OCN + ocb * 4 + oc)) * HH + h0 + o) * WW + 2 * jj) = v;
        }
}

// ---------- f32 fallback if ws is too small ----------
#define NEGINF (-INFINITY)
__global__ __launch_bounds__(192, 8) void semiconv2d_f32(
    const float* __restrict__ x, const float* __restrict__ kk, float* __restrict__ out)
{
    const int tid = threadIdx.x;
    const int w  = tid % WW;
    const int hr = tid / WW;
    const int b   = blockIdx.x;
    const int ocb = b & 7;
    const int hp  = (b >> 3) % 48;
    const int n   = (b >> 3) / 48;
    const int h   = hp * 2 + hr;
    const int oc0 = ocb * 4;
    float a0[4], a1[4], a2[4];
#pragma unroll
    for (int i = 0; i < 4; ++i) { a0[i] = NEGINF; a1[i] = NEGINF; a2[i] = NEGINF; }
    const bool vm = (h > 0), vp = (h < HH - 1);
    const int hm  = vm ? h - 1 : h;
    const int hpl = vp ? h + 1 : h;
    const int cm  = (w > 0) ? -1 : 0;
    const int cp  = (w < WW - 1) ? 1 : 0;
    const float* rm = x + ((size_t)(n * CIN) * HH + hm)  * WW + w;
    const float* r1 = x + ((size_t)(n * CIN) * HH + h)   * WW + w;
    const float* rp = x + ((size_t)(n * CIN) * HH + hpl) * WW + w;
#pragma unroll 2
    for (int ic = 0; ic < CIN; ++ic) {
        float r00 = vm ? rm[cm] : NEGINF, r01 = vm ? rm[0] : NEGINF, r02 = vm ? rm[cp] : NEGINF;
        float r10 = r1[cm], r11 = r1[0], r12 = r1[cp];
        float r20 = vp ? rp[cm] : NEGINF, r21 = vp ? rp[0] : NEGINF, r22 = vp ? rp[cp] : NEGINF;
#pragma unroll
        for (int oc = 0; oc < 4; ++oc) {
            const float* kq = kk + (size_t)(((oc0 + oc) * CIN + ic)) * 9;
            a0[oc] = fmaxf(fmaxf(a0[oc], fminf(r00, kq[0])), fmaxf(fminf(r10, kq[3]), fminf(r20, kq[6])));
            a1[oc] = fmaxf(fmaxf(a1[oc], fminf(r01, kq[1])), fmaxf(fminf(r11, kq[4]), fminf(r21, kq[7])));
            a2[oc] = fmaxf(fmaxf(a2[oc], fminf(r02, kq[2])), fmaxf(fminf(r12, kq[5]), fminf(r22, kq[8])));
        }
        rm += HH * WW; r1 += HH * WW; rp += HH * WW;
    }
#pragma unroll
    for (int oc = 0; oc < 4; ++oc) {
        float v0 = (w > 0)      ? a0[oc] : NEGINF;
        float v2 = (w < WW - 1) ? a2[oc] : NEGINF;
        out[(((size_t)(n * OCN + oc0 + oc)) * HH + h) * WW + w] = fmaxf(fmaxf(v0, a1[oc]), v2);
    }
}

extern "C" void kernel_launch(void* const* d_in, const int* in_sizes, int n_in,
                              void* d_out, int out_size, void* d_ws, size_t ws_size,
                              hipStream_t stream) {
    const float* x  = (const float*)d_in[0];
    const float* kk = (const float*)d_in[1];
    float* out      = (float*)d_out;
    if (ws_size >= WS_NEED) {
        uint4* xq2     = (uint4*)d_ws;
        uint32_t* kpck = (uint32_t*)(xq2 + XQ_TOTAL);
        setup_xq2<<<dim3(XQ_TOTAL / 256), dim3(256), 0, stream>>>(x, xq2);
        setup_kp<<<dim3(KP_TOTAL / 256), dim3(256), 0, stream>>>(kk, kpck);
        semiconv_f16<<<dim3(8 * 8 * 12), dim3(192), 0, stream>>>(xq2, kpck, out);
    } else {
        semiconv2d_f32<<<dim3(8 * 48 * 8), dim3(192), 0, stream>>>(x, kk, out);
    }
}